// Round 1
// baseline (1952.150 us; speedup 1.0000x reference)
//
#include <hip/hip_runtime.h>
#include <math.h>

#define B_    16384
#define IN_   64
#define DENC_ 512
#define NE_   2048
#define P_    12
#define ROWS_ 196608      // B_*P_
#define BETA_ 0.25

// output layout (all float32, concatenated in return order)
#define XHAT_OFF 1
#define PERP_OFF 1048577   // 1 + 16384*64
#define IDXF_OFF 1048578
#define COEF_OFF 1245186   // IDXF_OFF + 196608

// ---------------------------------------------------------------------------
// Generic tiled f32 GEMM with bias: C[M][N] = A[M][K] @ W[K][N] + bias[N]
// BM=BN=64, BK=64, 256 threads, thread computes 4x4.
// ---------------------------------------------------------------------------
__global__ __launch_bounds__(256) void k_gemm_bias(const float* __restrict__ A,
                                                   const float* __restrict__ W,
                                                   const float* __restrict__ bias,
                                                   float* __restrict__ C,
                                                   int M, int N, int K) {
    __shared__ float aT[64][68];
    __shared__ float wT[64][68];
    const int tid = threadIdx.x;
    const int n0 = blockIdx.x * 64;
    const int m0 = blockIdx.y * 64;
    const int tr = tid >> 4;   // 0..15 -> rows tr*4..
    const int tc = tid & 15;   // 0..15 -> cols tc*4..

    float acc[4][4];
#pragma unroll
    for (int i = 0; i < 4; ++i)
#pragma unroll
        for (int j = 0; j < 4; ++j) acc[i][j] = 0.0f;

    for (int k0 = 0; k0 < K; k0 += 64) {
        // stage A tile and W tile (transposed)
#pragma unroll
        for (int it = 0; it < 4; ++it) {
            int f = tid + it * 256;          // 0..1023 float4 slots
            int r = f >> 4, q = f & 15;
            float4 av = *(const float4*)(A + (size_t)(m0 + r) * K + k0 + q * 4);
            *(float4*)(&aT[r][q * 4]) = av;
            float4 wv = *(const float4*)(W + (size_t)(k0 + r) * N + n0 + q * 4);
            wT[q * 4 + 0][r] = wv.x;
            wT[q * 4 + 1][r] = wv.y;
            wT[q * 4 + 2][r] = wv.z;
            wT[q * 4 + 3][r] = wv.w;
        }
        __syncthreads();

        for (int k = 0; k < 64; k += 4) {
            float4 av[4], wv[4];
#pragma unroll
            for (int i = 0; i < 4; ++i) av[i] = *(float4*)(&aT[tr * 4 + i][k]);
#pragma unroll
            for (int j = 0; j < 4; ++j) wv[j] = *(float4*)(&wT[tc * 4 + j][k]);
#pragma unroll
            for (int i = 0; i < 4; ++i)
#pragma unroll
                for (int j = 0; j < 4; ++j) {
                    acc[i][j] += av[i].x * wv[j].x;
                    acc[i][j] += av[i].y * wv[j].y;
                    acc[i][j] += av[i].z * wv[j].z;
                    acc[i][j] += av[i].w * wv[j].w;
                }
        }
        __syncthreads();
    }

    float4 bv = *(const float4*)(bias + n0 + tc * 4);
#pragma unroll
    for (int i = 0; i < 4; ++i) {
        float4 o;
        o.x = acc[i][0] + bv.x;
        o.y = acc[i][1] + bv.y;
        o.z = acc[i][2] + bv.z;
        o.w = acc[i][3] + bv.w;
        *(float4*)(C + (size_t)(m0 + tr * 4 + i) * N + n0 + tc * 4) = o;
    }
}

// ---------------------------------------------------------------------------
// h = h + relu(layer_norm(t) * g + beta), rowwise over 512. One wave per row.
// ---------------------------------------------------------------------------
__global__ __launch_bounds__(256) void k_lnrelu(const float* __restrict__ t,
                                                float* __restrict__ h,
                                                const float* __restrict__ g,
                                                const float* __restrict__ beta) {
    const int tid = threadIdx.x;
    const int wv = tid >> 6, lane = tid & 63;
    const int row = blockIdx.x * 4 + wv;
    const float* tr = t + (size_t)row * DENC_;
    float* hr = h + (size_t)row * DENC_;

    float4 v0 = *(const float4*)(tr + lane * 4);
    float4 v1 = *(const float4*)(tr + 256 + lane * 4);

    float s = v0.x + v0.y + v0.z + v0.w + v1.x + v1.y + v1.z + v1.w;
#pragma unroll
    for (int m = 1; m < 64; m <<= 1) s += __shfl_xor(s, m);
    float mu = s / 512.0f;

    float d0x = v0.x - mu, d0y = v0.y - mu, d0z = v0.z - mu, d0w = v0.w - mu;
    float d1x = v1.x - mu, d1y = v1.y - mu, d1z = v1.z - mu, d1w = v1.w - mu;
    float vs = d0x * d0x + d0y * d0y + d0z * d0z + d0w * d0w +
               d1x * d1x + d1y * d1y + d1z * d1z + d1w * d1w;
#pragma unroll
    for (int m = 1; m < 64; m <<= 1) vs += __shfl_xor(vs, m);
    float var = vs / 512.0f;
    float rs = (float)(1.0 / sqrt((double)var + 1e-5));

    float4 g0 = *(const float4*)(g + lane * 4);
    float4 g1 = *(const float4*)(g + 256 + lane * 4);
    float4 b0 = *(const float4*)(beta + lane * 4);
    float4 b1 = *(const float4*)(beta + 256 + lane * 4);

    float4 h0 = *(float4*)(hr + lane * 4);
    float4 h1 = *(float4*)(hr + 256 + lane * 4);

    h0.x += fmaxf(d0x * rs * g0.x + b0.x, 0.0f);
    h0.y += fmaxf(d0y * rs * g0.y + b0.y, 0.0f);
    h0.z += fmaxf(d0z * rs * g0.z + b0.z, 0.0f);
    h0.w += fmaxf(d0w * rs * g0.w + b0.w, 0.0f);
    h1.x += fmaxf(d1x * rs * g1.x + b1.x, 0.0f);
    h1.y += fmaxf(d1y * rs * g1.y + b1.y, 0.0f);
    h1.z += fmaxf(d1z * rs * g1.z + b1.z, 0.0f);
    h1.w += fmaxf(d1w * rs * g1.w + b1.w, 0.0f);

    *(float4*)(hr + lane * 4) = h0;
    *(float4*)(hr + 256 + lane * 4) = h1;
}

// ---------------------------------------------------------------------------
// se[c] = sum(emb[c]^2)
// ---------------------------------------------------------------------------
__global__ void k_esq(const float* __restrict__ emb, float* __restrict__ se) {
    int t = blockIdx.x * 256 + threadIdx.x;
    if (t < NE_) {
        float s = 0.0f;
        for (int k = 0; k < 64; ++k) {
            float v = emb[(size_t)t * 64 + k];
            s += v * v;
        }
        se[t] = s;
    }
}

// ---------------------------------------------------------------------------
// distances + argmin. WG covers 64 z-rows x all 2048 codewords in chunks of 64.
// thread = 4 rows x 4 codewords. d = (sz + se) - 2*dot (f32, matches jax assoc).
// ---------------------------------------------------------------------------
__global__ __launch_bounds__(256) void k_dist(const float* __restrict__ z,
                                              const float* __restrict__ emb,
                                              const float* __restrict__ se,
                                              int* __restrict__ idxw,
                                              float* __restrict__ idxf,
                                              float* __restrict__ dminw,
                                              int* __restrict__ counts) {
    __shared__ float zt[64][68];
    __shared__ float et[64][68];
    __shared__ float szs[64];
    __shared__ float cd[64][16];
    __shared__ int ci[64][16];

    const int tid = threadIdx.x;
    const int row0 = blockIdx.x * 64;
    const int tr = tid & 15;   // row group
    const int tg = tid >> 4;   // codeword group

    // stage z tile
#pragma unroll
    for (int it = 0; it < 4; ++it) {
        int f = tid + it * 256;
        int r = f >> 4, q = f & 15;
        *(float4*)(&zt[r][q * 4]) = *(const float4*)(z + (size_t)(row0 + r) * 64 + q * 4);
    }
    __syncthreads();
    if (tid < 64) {
        float s = 0.0f;
        for (int k = 0; k < 64; ++k) {
            float v = zt[tid][k];
            s += v * v;
        }
        szs[tid] = s;
    }

    float bd[4];
    int bi[4];
#pragma unroll
    for (int i = 0; i < 4; ++i) { bd[i] = 1e30f; bi[i] = 0; }

    for (int ch = 0; ch < 32; ++ch) {
        int c0 = ch * 64;
#pragma unroll
        for (int it = 0; it < 4; ++it) {
            int f = tid + it * 256;
            int r = f >> 4, q = f & 15;
            *(float4*)(&et[r][q * 4]) = *(const float4*)(emb + (size_t)(c0 + r) * 64 + q * 4);
        }
        __syncthreads();

        float acc[4][4];
#pragma unroll
        for (int i = 0; i < 4; ++i)
#pragma unroll
            for (int j = 0; j < 4; ++j) acc[i][j] = 0.0f;

        for (int k = 0; k < 64; k += 4) {
            float4 av[4], ev[4];
#pragma unroll
            for (int i = 0; i < 4; ++i) av[i] = *(float4*)(&zt[tr * 4 + i][k]);
#pragma unroll
            for (int j = 0; j < 4; ++j) ev[j] = *(float4*)(&et[tg * 4 + j][k]);
#pragma unroll
            for (int i = 0; i < 4; ++i)
#pragma unroll
                for (int j = 0; j < 4; ++j) {
                    acc[i][j] += av[i].x * ev[j].x;
                    acc[i][j] += av[i].y * ev[j].y;
                    acc[i][j] += av[i].z * ev[j].z;
                    acc[i][j] += av[i].w * ev[j].w;
                }
        }

#pragma unroll
        for (int j = 0; j < 4; ++j) {
            int c = c0 + tg * 4 + j;
            float sec = se[c];
#pragma unroll
            for (int i = 0; i < 4; ++i) {
                float d = (szs[tr * 4 + i] + sec) - 2.0f * acc[i][j];
                if (d < bd[i]) { bd[i] = d; bi[i] = c; }
            }
        }
        __syncthreads();
    }

#pragma unroll
    for (int i = 0; i < 4; ++i) {
        cd[tr * 4 + i][tg] = bd[i];
        ci[tr * 4 + i][tg] = bi[i];
    }
    __syncthreads();

    if (tid < 64) {
        float best = cd[tid][0];
        int bidx = ci[tid][0];
        for (int g = 1; g < 16; ++g) {
            float d = cd[tid][g];
            int ii = ci[tid][g];
            if (d < best || (d == best && ii < bidx)) { best = d; bidx = ii; }
        }
        int grow = row0 + tid;
        idxw[grow] = bidx;
        idxf[grow] = (float)bidx;
        dminw[grow] = best;
        atomicAdd(&counts[bidx], 1);
    }
}

// ---------------------------------------------------------------------------
// loss (from sum of dmin) and perplexity (from counts). One block, 1024 threads.
// ---------------------------------------------------------------------------
__global__ __launch_bounds__(1024) void k_lossperp(const float* __restrict__ dmin,
                                                   const int* __restrict__ counts,
                                                   float* __restrict__ out) {
    __shared__ double red[1024];
    const int tid = threadIdx.x;

    double s = 0.0;
    for (int i = tid; i < ROWS_; i += 1024) s += (double)dmin[i];
    red[tid] = s;
    __syncthreads();
    for (int off = 512; off > 0; off >>= 1) {
        if (tid < off) red[tid] += red[tid + off];
        __syncthreads();
    }
    if (tid == 0) out[0] = (float)(red[0] * (1.0 + BETA_) / ((double)ROWS_ * IN_));
    __syncthreads();

    double hsum = 0.0;
    for (int i = tid; i < NE_; i += 1024) {
        float p = (float)counts[i] / 196608.0f;
        float lg = logf(p + 1e-10f);
        hsum += (double)(p * lg);
    }
    red[tid] = hsum;
    __syncthreads();
    for (int off = 512; off > 0; off >>= 1) {
        if (tid < off) red[tid] += red[tid + off];
        __syncthreads();
    }
    if (tid == 0) out[PERP_OFF] = (float)exp(-red[0]);
}

// ---------------------------------------------------------------------------
// per-block pinv least-squares: coeff + x_hat. One wave per weight-block.
// Dedup duplicate codeword columns -> min-norm solution matching pinv.
// fp64 normal equations + Cholesky.
// ---------------------------------------------------------------------------
__global__ __launch_bounds__(256) void k_pinv(const float* __restrict__ xin,
                                              const float* __restrict__ emb,
                                              const int* __restrict__ idxw,
                                              float* __restrict__ coeff,
                                              float* __restrict__ xhat) {
    __shared__ float aS[4][12][65];
    __shared__ float xS[4][64];
    __shared__ double GS[4][12][12];
    __shared__ double bS[4][12];
    __shared__ double uS[4][12];
    __shared__ float cS[4][12];

    const int tid = threadIdx.x;
    const int wv = tid >> 6, lane = tid & 63;
    const int b = blockIdx.x * 4 + wv;

    int my = 0;
    if (lane < 12) my = idxw[(size_t)b * 12 + lane];
    int id[12];
#pragma unroll
    for (int p = 0; p < 12; ++p) id[p] = __shfl(my, p);

    // dedup: first occurrence + multiplicity
    int rep = lane, mcnt = 1;
    if (lane < 12) {
        rep = -1;
        mcnt = 0;
        for (int q = 0; q < 12; ++q) {
            if (id[q] == id[lane]) {
                if (rep < 0) rep = q;
                mcnt++;
            }
        }
    }

#pragma unroll
    for (int p = 0; p < 12; ++p) aS[wv][p][lane] = emb[(size_t)id[p] * 64 + lane];
    xS[wv][lane] = xin[(size_t)b * 64 + lane];
    __syncthreads();

    // Gram + rhs in fp64
    for (int item = lane; item < 90; item += 64) {
        if (item < 78) {
            int j = 0, k = 0, c = item;
            for (j = 0; j < 12; ++j) {
                int cnt = 12 - j;
                if (c < cnt) { k = j + c; break; }
                c -= cnt;
            }
            double s = 0.0;
            for (int t = 0; t < 64; ++t) s += (double)aS[wv][j][t] * (double)aS[wv][k][t];
            GS[wv][j][k] = s;
            GS[wv][k][j] = s;
        } else {
            int j = item - 78;
            double s = 0.0;
            for (int t = 0; t < 64; ++t) s += (double)aS[wv][j][t] * (double)xS[wv][t];
            bS[wv][j] = s;
        }
    }
    __syncthreads();

    // mask duplicate rows/cols -> identity
    if (lane == 0) {
        for (int p = 0; p < 12; ++p) {
            int rp = -1;
            for (int q = 0; q < 12; ++q) {
                if (id[q] == id[p]) { rp = q; break; }
            }
            if (rp != p) {
                for (int q = 0; q < 12; ++q) {
                    GS[wv][p][q] = 0.0;
                    GS[wv][q][p] = 0.0;
                }
                GS[wv][p][p] = 1.0;
                bS[wv][p] = 0.0;
            }
        }
    }
    __syncthreads();

    // Cholesky (lower, in place), column-parallel across 12 lanes
    for (int j = 0; j < 12; ++j) {
        if (lane == j) {
            double s = GS[wv][j][j];
            for (int k = 0; k < j; ++k) {
                double l = GS[wv][j][k];
                s -= l * l;
            }
            GS[wv][j][j] = sqrt(fmax(s, 1e-30));
        }
        __syncthreads();
        if (lane > j && lane < 12) {
            double s = GS[wv][lane][j];
            for (int k = 0; k < j; ++k) s -= GS[wv][lane][k] * GS[wv][j][k];
            GS[wv][lane][j] = s / GS[wv][j][j];
        }
        __syncthreads();
    }

    if (lane == 0) {
        double y[12];
        for (int i = 0; i < 12; ++i) {
            double s = bS[wv][i];
            for (int k = 0; k < i; ++k) s -= GS[wv][i][k] * y[k];
            y[i] = s / GS[wv][i][i];
        }
        for (int i = 11; i >= 0; --i) {
            double s = y[i];
            for (int k = i + 1; k < 12; ++k) s -= GS[wv][k][i] * uS[wv][k];
            uS[wv][i] = s / GS[wv][i][i];
        }
    }
    __syncthreads();

    if (lane < 12) {
        double c = uS[wv][rep] / (double)mcnt;
        coeff[(size_t)b * 12 + lane] = (float)c;
        cS[wv][lane] = (float)c;
    }
    __syncthreads();

    float s = 0.0f;
#pragma unroll
    for (int p = 0; p < 12; ++p) s += aS[wv][p][lane] * cS[wv][p];
    xhat[(size_t)b * 64 + lane] = s;
}

// ---------------------------------------------------------------------------

extern "C" void kernel_launch(void* const* d_in, const int* in_sizes, int n_in,
                              void* d_out, int out_size, void* d_ws, size_t ws_size,
                              hipStream_t stream) {
    const float* x        = (const float*)d_in[0];
    const float* enc_w1   = (const float*)d_in[1];
    const float* enc_b1   = (const float*)d_in[2];
    const float* res_w    = (const float*)d_in[3];
    const float* res_b    = (const float*)d_in[4];
    const float* res_g    = (const float*)d_in[5];
    const float* res_beta = (const float*)d_in[6];
    const float* enc_w2   = (const float*)d_in[7];
    const float* enc_b2   = (const float*)d_in[8];
    const float* emb      = (const float*)d_in[9];

    float* out = (float*)d_out;

    // workspace layout
    float* h  = (float*)d_ws;            // B*512 f32 (32MB), reused after enc2
    float* tz = h + (size_t)B_ * DENC_;  // B*768 f32 (48MB): t (resblock tmp) then z
    // reuse of h region after enc2:
    float* se   = h;                          // 2048
    float* dmin = h + 2048;                   // ROWS_
    int* idxw   = (int*)(h + 2048 + ROWS_);   // ROWS_
    int* cnts   = (int*)(h + 2048 + 2 * (size_t)ROWS_); // 2048

    float* t = tz;  // B*512 region within tz
    float* z = tz;  // B*768 after resblocks

    // encoder
    k_gemm_bias<<<dim3(DENC_ / 64, B_ / 64), 256, 0, stream>>>(x, enc_w1, enc_b1, h, B_, DENC_, IN_);
    for (int r = 0; r < 2; ++r) {
        k_gemm_bias<<<dim3(DENC_ / 64, B_ / 64), 256, 0, stream>>>(h, res_w, res_b, t, B_, DENC_, DENC_);
        k_lnrelu<<<B_ / 4, 256, 0, stream>>>(t, h, res_g, res_beta);
    }
    k_gemm_bias<<<dim3(768 / 64, B_ / 64), 256, 0, stream>>>(h, enc_w2, enc_b2, z, B_, 768, DENC_);

    // h region now dead -> se/dmin/idx/counts live there
    hipMemsetAsync(cnts, 0, NE_ * sizeof(int), stream);
    k_esq<<<NE_ / 256, 256, 0, stream>>>(emb, se);
    k_dist<<<ROWS_ / 64, 256, 0, stream>>>(z, emb, se, idxw, out + IDXF_OFF, dmin, cnts);
    k_lossperp<<<1, 1024, 0, stream>>>(dmin, cnts, out);
    k_pinv<<<B_ / 4, 256, 0, stream>>>(x, emb, idxw, out + COEF_OFF, out + XHAT_OFF);
}

// Round 2
// 1202.334 us; speedup vs baseline: 1.6236x; 1.6236x over previous
//
#include <hip/hip_runtime.h>
#include <math.h>

#define B_    16384
#define IN_   64
#define DENC_ 512
#define NE_   2048
#define P_    12
#define ROWS_ 196608      // B_*P_
#define BETA_ 0.25

// output layout (all float32, concatenated in return order)
#define XHAT_OFF 1
#define PERP_OFF 1048577   // 1 + 16384*64
#define IDXF_OFF 1048578
#define COEF_OFF 1245186   // IDXF_OFF + 196608

typedef __bf16 bf16x8 __attribute__((ext_vector_type(8)));
typedef float  f32x16 __attribute__((ext_vector_type(16)));

__device__ __forceinline__ void split3(float v, __bf16& h, __bf16& m, __bf16& l) {
    h = (__bf16)v;
    float r1 = v - (float)h;
    m = (__bf16)r1;
    float r2 = r1 - (float)m;
    l = (__bf16)r2;
}

// ---------------------------------------------------------------------------
// Generic tiled f32 GEMM with bias: C[M][N] = A[M][K] @ W[K][N] + bias[N]
// ---------------------------------------------------------------------------
__global__ __launch_bounds__(256) void k_gemm_bias(const float* __restrict__ A,
                                                   const float* __restrict__ W,
                                                   const float* __restrict__ bias,
                                                   float* __restrict__ C,
                                                   int M, int N, int K) {
    __shared__ float aT[64][68];
    __shared__ float wT[64][68];
    const int tid = threadIdx.x;
    const int n0 = blockIdx.x * 64;
    const int m0 = blockIdx.y * 64;
    const int tr = tid >> 4;
    const int tc = tid & 15;

    float acc[4][4];
#pragma unroll
    for (int i = 0; i < 4; ++i)
#pragma unroll
        for (int j = 0; j < 4; ++j) acc[i][j] = 0.0f;

    for (int k0 = 0; k0 < K; k0 += 64) {
#pragma unroll
        for (int it = 0; it < 4; ++it) {
            int f = tid + it * 256;
            int r = f >> 4, q = f & 15;
            float4 av = *(const float4*)(A + (size_t)(m0 + r) * K + k0 + q * 4);
            *(float4*)(&aT[r][q * 4]) = av;
            float4 wv = *(const float4*)(W + (size_t)(k0 + r) * N + n0 + q * 4);
            wT[q * 4 + 0][r] = wv.x;
            wT[q * 4 + 1][r] = wv.y;
            wT[q * 4 + 2][r] = wv.z;
            wT[q * 4 + 3][r] = wv.w;
        }
        __syncthreads();

        for (int k = 0; k < 64; k += 4) {
            float4 av[4], wv[4];
#pragma unroll
            for (int i = 0; i < 4; ++i) av[i] = *(float4*)(&aT[tr * 4 + i][k]);
#pragma unroll
            for (int j = 0; j < 4; ++j) wv[j] = *(float4*)(&wT[tc * 4 + j][k]);
#pragma unroll
            for (int i = 0; i < 4; ++i)
#pragma unroll
                for (int j = 0; j < 4; ++j) {
                    acc[i][j] += av[i].x * wv[j].x;
                    acc[i][j] += av[i].y * wv[j].y;
                    acc[i][j] += av[i].z * wv[j].z;
                    acc[i][j] += av[i].w * wv[j].w;
                }
        }
        __syncthreads();
    }

    float4 bv = *(const float4*)(bias + n0 + tc * 4);
#pragma unroll
    for (int i = 0; i < 4; ++i) {
        float4 o;
        o.x = acc[i][0] + bv.x;
        o.y = acc[i][1] + bv.y;
        o.z = acc[i][2] + bv.z;
        o.w = acc[i][3] + bv.w;
        *(float4*)(C + (size_t)(m0 + tr * 4 + i) * N + n0 + tc * 4) = o;
    }
}

// ---------------------------------------------------------------------------
// h = h + relu(layer_norm(t) * g + beta)
// ---------------------------------------------------------------------------
__global__ __launch_bounds__(256) void k_lnrelu(const float* __restrict__ t,
                                                float* __restrict__ h,
                                                const float* __restrict__ g,
                                                const float* __restrict__ beta) {
    const int tid = threadIdx.x;
    const int wv = tid >> 6, lane = tid & 63;
    const int row = blockIdx.x * 4 + wv;
    const float* tr = t + (size_t)row * DENC_;
    float* hr = h + (size_t)row * DENC_;

    float4 v0 = *(const float4*)(tr + lane * 4);
    float4 v1 = *(const float4*)(tr + 256 + lane * 4);

    float s = v0.x + v0.y + v0.z + v0.w + v1.x + v1.y + v1.z + v1.w;
#pragma unroll
    for (int m = 1; m < 64; m <<= 1) s += __shfl_xor(s, m);
    float mu = s / 512.0f;

    float d0x = v0.x - mu, d0y = v0.y - mu, d0z = v0.z - mu, d0w = v0.w - mu;
    float d1x = v1.x - mu, d1y = v1.y - mu, d1z = v1.z - mu, d1w = v1.w - mu;
    float vs = d0x * d0x + d0y * d0y + d0z * d0z + d0w * d0w +
               d1x * d1x + d1y * d1y + d1z * d1z + d1w * d1w;
#pragma unroll
    for (int m = 1; m < 64; m <<= 1) vs += __shfl_xor(vs, m);
    float var = vs / 512.0f;
    float rs = (float)(1.0 / sqrt((double)var + 1e-5));

    float4 g0 = *(const float4*)(g + lane * 4);
    float4 g1 = *(const float4*)(g + 256 + lane * 4);
    float4 b0 = *(const float4*)(beta + lane * 4);
    float4 b1 = *(const float4*)(beta + 256 + lane * 4);

    float4 h0 = *(float4*)(hr + lane * 4);
    float4 h1 = *(float4*)(hr + 256 + lane * 4);

    h0.x += fmaxf(d0x * rs * g0.x + b0.x, 0.0f);
    h0.y += fmaxf(d0y * rs * g0.y + b0.y, 0.0f);
    h0.z += fmaxf(d0z * rs * g0.z + b0.z, 0.0f);
    h0.w += fmaxf(d0w * rs * g0.w + b0.w, 0.0f);
    h1.x += fmaxf(d1x * rs * g1.x + b1.x, 0.0f);
    h1.y += fmaxf(d1y * rs * g1.y + b1.y, 0.0f);
    h1.z += fmaxf(d1z * rs * g1.z + b1.z, 0.0f);
    h1.w += fmaxf(d1w * rs * g1.w + b1.w, 0.0f);

    *(float4*)(hr + lane * 4) = h0;
    *(float4*)(hr + 256 + lane * 4) = h1;
}

// ---------------------------------------------------------------------------
// E -> se + 3-way bf16 split planes (hi/mid/lo), one thread per codeword.
// ---------------------------------------------------------------------------
__global__ void k_esplit(const float* __restrict__ emb, float* __restrict__ se,
                         __bf16* __restrict__ Ehi, __bf16* __restrict__ Emid,
                         __bf16* __restrict__ Elo) {
    int c = blockIdx.x * 256 + threadIdx.x;
    if (c < NE_) {
        float s = 0.0f;
        for (int k = 0; k < 64; ++k) {
            float v = emb[(size_t)c * 64 + k];
            s += v * v;
            __bf16 h, m, l;
            split3(v, h, m, l);
            Ehi[(size_t)c * 64 + k] = h;
            Emid[(size_t)c * 64 + k] = m;
            Elo[(size_t)c * 64 + k] = l;
        }
        se[c] = s;
    }
}

// ---------------------------------------------------------------------------
// sz[row] = sum(z[row]^2). 4 threads/row, coalesced float4.
// ---------------------------------------------------------------------------
__global__ __launch_bounds__(256) void k_rowsq(const float* __restrict__ z,
                                               float* __restrict__ sz) {
    const int tid = threadIdx.x;
    const int row = blockIdx.x * 64 + (tid >> 2);
    const int part = tid & 3;
    const float4* zp = (const float4*)(z + (size_t)row * 64) + part * 4;
    float s = 0.0f;
#pragma unroll
    for (int i = 0; i < 4; ++i) {
        float4 v = zp[i];
        s += v.x * v.x + v.y * v.y + v.z * v.z + v.w * v.w;
    }
    s += __shfl_xor(s, 1);
    s += __shfl_xor(s, 2);
    if (part == 0) sz[row] = s;
}

// ---------------------------------------------------------------------------
// MFMA distance + argmin. Block = 128 rows (4 waves x 32), iterate all 2048
// codewords in 64-col chunks. Triple-split bf16, 6 MFMAs per k-chunk pair.
// d = (sz + se) - 2*dot, first-index tie semantics.
// ---------------------------------------------------------------------------
__global__ __launch_bounds__(256) void k_distm(const float* __restrict__ z,
                                               const float* __restrict__ se,
                                               const float* __restrict__ sz,
                                               const __bf16* __restrict__ Ehi,
                                               const __bf16* __restrict__ Emid,
                                               const __bf16* __restrict__ Elo,
                                               int* __restrict__ idxw,
                                               float* __restrict__ idxf,
                                               float* __restrict__ dminw,
                                               int* __restrict__ counts) {
    __shared__ __bf16 eS[3][64 * 64];   // XOR-swizzled 16B granules, 24.6 KB

    const int tid = threadIdx.x;
    const int w = tid >> 6, lane = tid & 63;
    const int r0 = blockIdx.x * 128 + w * 32;
    const int lrow = lane & 31;      // A-frag row / C col
    const int half = lane >> 5;

    // ---- A fragments: 3-way split of z rows, kept for whole kernel ----
    bf16x8 ah[4], am[4], al[4];
    {
        const float* zr = z + (size_t)(r0 + lrow) * 64 + half * 8;
#pragma unroll
        for (int kc = 0; kc < 4; ++kc) {
            float4 u0 = *(const float4*)(zr + kc * 16);
            float4 u1 = *(const float4*)(zr + kc * 16 + 4);
            float v[8] = {u0.x, u0.y, u0.z, u0.w, u1.x, u1.y, u1.z, u1.w};
#pragma unroll
            for (int j = 0; j < 8; ++j) {
                __bf16 hh, mm, ll;
                split3(v[j], hh, mm, ll);
                ah[kc][j] = hh; am[kc][j] = mm; al[kc][j] = ll;
            }
        }
    }

    // sz per accumulator register slot (broadcast across the 32-lane half)
    float szv[16];
#pragma unroll
    for (int r = 0; r < 16; ++r) {
        int rl = (r & 3) + 8 * (r >> 2) + 4 * half;
        szv[r] = sz[r0 + rl];
    }

    float bd[16];
    int bi[16];
#pragma unroll
    for (int r = 0; r < 16; ++r) { bd[r] = 1e30f; bi[r] = 0; }

    for (int ch = 0; ch < 32; ++ch) {
        const int c0 = ch * 64;
        __syncthreads();
        // stage 3 planes of the 64-col chunk, XOR-swizzled granules
        {
            const int col = tid >> 3, q = tid & 7;
#pragma unroll
            for (int p = 0; p < 2; ++p) {
                int cc = col + 32 * p;
                int g = q ^ (cc & 7);
                size_t soff = (size_t)(c0 + cc) * 64 + q * 8;
                int doff = cc * 64 + g * 8;
                *(float4*)(&eS[0][doff]) = *(const float4*)(Ehi + soff);
                *(float4*)(&eS[1][doff]) = *(const float4*)(Emid + soff);
                *(float4*)(&eS[2][doff]) = *(const float4*)(Elo + soff);
            }
        }
        __syncthreads();

        f32x16 acc0, acc1;
#pragma unroll
        for (int i = 0; i < 16; ++i) { acc0[i] = 0.0f; acc1[i] = 0.0f; }

#pragma unroll
        for (int kc = 0; kc < 4; ++kc) {
            const int q = kc * 2 + half;
            const int cL0 = lrow, cL1 = lrow + 32;
            const int g0 = (q ^ (cL0 & 7)) * 8, g1 = (q ^ (cL1 & 7)) * 8;
            bf16x8 b0h = *(const bf16x8*)(&eS[0][cL0 * 64 + g0]);
            bf16x8 b0m = *(const bf16x8*)(&eS[1][cL0 * 64 + g0]);
            bf16x8 b0l = *(const bf16x8*)(&eS[2][cL0 * 64 + g0]);
            bf16x8 b1h = *(const bf16x8*)(&eS[0][cL1 * 64 + g1]);
            bf16x8 b1m = *(const bf16x8*)(&eS[1][cL1 * 64 + g1]);
            bf16x8 b1l = *(const bf16x8*)(&eS[2][cL1 * 64 + g1]);

            acc0 = __builtin_amdgcn_mfma_f32_32x32x16_bf16(ah[kc], b0h, acc0, 0, 0, 0);
            acc1 = __builtin_amdgcn_mfma_f32_32x32x16_bf16(ah[kc], b1h, acc1, 0, 0, 0);
            acc0 = __builtin_amdgcn_mfma_f32_32x32x16_bf16(ah[kc], b0m, acc0, 0, 0, 0);
            acc1 = __builtin_amdgcn_mfma_f32_32x32x16_bf16(ah[kc], b1m, acc1, 0, 0, 0);
            acc0 = __builtin_amdgcn_mfma_f32_32x32x16_bf16(am[kc], b0h, acc0, 0, 0, 0);
            acc1 = __builtin_amdgcn_mfma_f32_32x32x16_bf16(am[kc], b1h, acc1, 0, 0, 0);
            acc0 = __builtin_amdgcn_mfma_f32_32x32x16_bf16(ah[kc], b0l, acc0, 0, 0, 0);
            acc1 = __builtin_amdgcn_mfma_f32_32x32x16_bf16(ah[kc], b1l, acc1, 0, 0, 0);
            acc0 = __builtin_amdgcn_mfma_f32_32x32x16_bf16(am[kc], b0m, acc0, 0, 0, 0);
            acc1 = __builtin_amdgcn_mfma_f32_32x32x16_bf16(am[kc], b1m, acc1, 0, 0, 0);
            acc0 = __builtin_amdgcn_mfma_f32_32x32x16_bf16(al[kc], b0h, acc0, 0, 0, 0);
            acc1 = __builtin_amdgcn_mfma_f32_32x32x16_bf16(al[kc], b1h, acc1, 0, 0, 0);
        }

        const float se0 = se[c0 + lrow];
        const float se1 = se[c0 + lrow + 32];
        const int   ci0 = c0 + lrow, ci1 = c0 + lrow + 32;
#pragma unroll
        for (int r = 0; r < 16; ++r) {
            float d0 = fmaf(-2.0f, acc0[r], szv[r] + se0);
            if (d0 < bd[r]) { bd[r] = d0; bi[r] = ci0; }
            float d1 = fmaf(-2.0f, acc1[r], szv[r] + se1);
            if (d1 < bd[r]) { bd[r] = d1; bi[r] = ci1; }
        }
    }

    // cross-lane argmin within each 32-lane half (lexicographic: d, then idx)
#pragma unroll
    for (int r = 0; r < 16; ++r) {
        float d = bd[r];
        int i = bi[r];
#pragma unroll
        for (int off = 1; off < 32; off <<= 1) {
            float od = __shfl_xor(d, off);
            int oi = __shfl_xor(i, off);
            if (od < d || (od == d && oi < i)) { d = od; i = oi; }
        }
        bd[r] = d; bi[r] = i;
    }

    if (lrow == 0) {
#pragma unroll
        for (int r = 0; r < 16; ++r) {
            int rl = (r & 3) + 8 * (r >> 2) + 4 * half;
            int row = r0 + rl;
            idxw[row] = bi[r];
            idxf[row] = (float)bi[r];
            dminw[row] = bd[r];
            atomicAdd(&counts[bi[r]], 1);
        }
    }
}

// ---------------------------------------------------------------------------
// loss + perplexity
// ---------------------------------------------------------------------------
__global__ __launch_bounds__(1024) void k_lossperp(const float* __restrict__ dmin,
                                                   const int* __restrict__ counts,
                                                   float* __restrict__ out) {
    __shared__ double red[1024];
    const int tid = threadIdx.x;

    double s = 0.0;
    for (int i = tid; i < ROWS_; i += 1024) s += (double)dmin[i];
    red[tid] = s;
    __syncthreads();
    for (int off = 512; off > 0; off >>= 1) {
        if (tid < off) red[tid] += red[tid + off];
        __syncthreads();
    }
    if (tid == 0) out[0] = (float)(red[0] * (1.0 + BETA_) / ((double)ROWS_ * IN_));
    __syncthreads();

    double hsum = 0.0;
    for (int i = tid; i < NE_; i += 1024) {
        float p = (float)counts[i] / 196608.0f;
        float lg = logf(p + 1e-10f);
        hsum += (double)(p * lg);
    }
    red[tid] = hsum;
    __syncthreads();
    for (int off = 512; off > 0; off >>= 1) {
        if (tid < off) red[tid] += red[tid + off];
        __syncthreads();
    }
    if (tid == 0) out[PERP_OFF] = (float)exp(-red[0]);
}

// ---------------------------------------------------------------------------
// per-block pinv least-squares: coeff + x_hat (dedup -> min-norm, f64 Cholesky)
// ---------------------------------------------------------------------------
__global__ __launch_bounds__(256) void k_pinv(const float* __restrict__ xin,
                                              const float* __restrict__ emb,
                                              const int* __restrict__ idxw,
                                              float* __restrict__ coeff,
                                              float* __restrict__ xhat) {
    __shared__ float aS[4][12][65];
    __shared__ float xS[4][64];
    __shared__ double GS[4][12][12];
    __shared__ double bS[4][12];
    __shared__ double uS[4][12];
    __shared__ float cS[4][12];

    const int tid = threadIdx.x;
    const int wv = tid >> 6, lane = tid & 63;
    const int b = blockIdx.x * 4 + wv;

    int my = 0;
    if (lane < 12) my = idxw[(size_t)b * 12 + lane];
    int id[12];
#pragma unroll
    for (int p = 0; p < 12; ++p) id[p] = __shfl(my, p);

    int rep = lane, mcnt = 1;
    if (lane < 12) {
        rep = -1;
        mcnt = 0;
        for (int q = 0; q < 12; ++q) {
            if (id[q] == id[lane]) {
                if (rep < 0) rep = q;
                mcnt++;
            }
        }
    }

#pragma unroll
    for (int p = 0; p < 12; ++p) aS[wv][p][lane] = emb[(size_t)id[p] * 64 + lane];
    xS[wv][lane] = xin[(size_t)b * 64 + lane];
    __syncthreads();

    for (int item = lane; item < 90; item += 64) {
        if (item < 78) {
            int j = 0, k = 0, c = item;
            for (j = 0; j < 12; ++j) {
                int cnt = 12 - j;
                if (c < cnt) { k = j + c; break; }
                c -= cnt;
            }
            double s = 0.0;
            for (int t = 0; t < 64; ++t) s += (double)aS[wv][j][t] * (double)aS[wv][k][t];
            GS[wv][j][k] = s;
            GS[wv][k][j] = s;
        } else {
            int j = item - 78;
            double s = 0.0;
            for (int t = 0; t < 64; ++t) s += (double)aS[wv][j][t] * (double)xS[wv][t];
            bS[wv][j] = s;
        }
    }
    __syncthreads();

    if (lane == 0) {
        for (int p = 0; p < 12; ++p) {
            int rp = -1;
            for (int q = 0; q < 12; ++q) {
                if (id[q] == id[p]) { rp = q; break; }
            }
            if (rp != p) {
                for (int q = 0; q < 12; ++q) {
                    GS[wv][p][q] = 0.0;
                    GS[wv][q][p] = 0.0;
                }
                GS[wv][p][p] = 1.0;
                bS[wv][p] = 0.0;
            }
        }
    }
    __syncthreads();

    for (int j = 0; j < 12; ++j) {
        if (lane == j) {
            double s = GS[wv][j][j];
            for (int k = 0; k < j; ++k) {
                double l = GS[wv][j][k];
                s -= l * l;
            }
            GS[wv][j][j] = sqrt(fmax(s, 1e-30));
        }
        __syncthreads();
        if (lane > j && lane < 12) {
            double s = GS[wv][lane][j];
            for (int k = 0; k < j; ++k) s -= GS[wv][lane][k] * GS[wv][j][k];
            GS[wv][lane][j] = s / GS[wv][j][j];
        }
        __syncthreads();
    }

    if (lane == 0) {
        double y[12];
        for (int i = 0; i < 12; ++i) {
            double s = bS[wv][i];
            for (int k = 0; k < i; ++k) s -= GS[wv][i][k] * y[k];
            y[i] = s / GS[wv][i][i];
        }
        for (int i = 11; i >= 0; --i) {
            double s = y[i];
            for (int k = i + 1; k < 12; ++k) s -= GS[wv][k][i] * uS[wv][k];
            uS[wv][i] = s / GS[wv][i][i];
        }
    }
    __syncthreads();

    if (lane < 12) {
        double c = uS[wv][rep] / (double)mcnt;
        coeff[(size_t)b * 12 + lane] = (float)c;
        cS[wv][lane] = (float)c;
    }
    __syncthreads();

    float s = 0.0f;
#pragma unroll
    for (int p = 0; p < 12; ++p) s += aS[wv][p][lane] * cS[wv][p];
    xhat[(size_t)b * 64 + lane] = s;
}

// ---------------------------------------------------------------------------

extern "C" void kernel_launch(void* const* d_in, const int* in_sizes, int n_in,
                              void* d_out, int out_size, void* d_ws, size_t ws_size,
                              hipStream_t stream) {
    const float* x        = (const float*)d_in[0];
    const float* enc_w1   = (const float*)d_in[1];
    const float* enc_b1   = (const float*)d_in[2];
    const float* res_w    = (const float*)d_in[3];
    const float* res_b    = (const float*)d_in[4];
    const float* res_g    = (const float*)d_in[5];
    const float* res_beta = (const float*)d_in[6];
    const float* enc_w2   = (const float*)d_in[7];
    const float* enc_b2   = (const float*)d_in[8];
    const float* emb      = (const float*)d_in[9];

    float* out = (float*)d_out;

    // workspace layout
    float* h  = (float*)d_ws;            // B*512 f32 (32MB), reused after enc2
    float* tz = h + (size_t)B_ * DENC_;  // B*768 f32 (48MB): t then z
    // reuse of h region after enc2:
    float* se    = h;                                        // 2048
    float* sz    = h + 2048;                                 // ROWS_
    float* dmin  = h + 2048 + (size_t)ROWS_;                 // ROWS_
    int*   idxw  = (int*)(h + 2048 + 2 * (size_t)ROWS_);     // ROWS_
    int*   cnts  = (int*)(h + 2048 + 3 * (size_t)ROWS_);     // 2048
    __bf16* Ehi  = (__bf16*)(h + 2048 + 3 * (size_t)ROWS_ + 2048);  // 16B-aligned
    __bf16* Emid = Ehi + (size_t)NE_ * 64;
    __bf16* Elo  = Emid + (size_t)NE_ * 64;

    float* t = tz;
    float* z = tz;

    // encoder (f32 path, unchanged)
    k_gemm_bias<<<dim3(DENC_ / 64, B_ / 64), 256, 0, stream>>>(x, enc_w1, enc_b1, h, B_, DENC_, IN_);
    for (int r = 0; r < 2; ++r) {
        k_gemm_bias<<<dim3(DENC_ / 64, B_ / 64), 256, 0, stream>>>(h, res_w, res_b, t, B_, DENC_, DENC_);
        k_lnrelu<<<B_ / 4, 256, 0, stream>>>(t, h, res_g, res_beta);
    }
    k_gemm_bias<<<dim3(768 / 64, B_ / 64), 256, 0, stream>>>(h, enc_w2, enc_b2, z, B_, 768, DENC_);

    // h region now dead -> prep for VQ
    hipMemsetAsync(cnts, 0, NE_ * sizeof(int), stream);
    k_esplit<<<NE_ / 256, 256, 0, stream>>>(emb, se, Ehi, Emid, Elo);
    k_rowsq<<<ROWS_ / 64, 256, 0, stream>>>(z, sz);
    k_distm<<<ROWS_ / 128, 256, 0, stream>>>(z, se, sz, Ehi, Emid, Elo,
                                             idxw, out + IDXF_OFF, dmin, cnts);
    k_lossperp<<<1, 1024, 0, stream>>>(dmin, cnts, out);
    k_pinv<<<B_ / 4, 256, 0, stream>>>(x, emb, idxw, out + COEF_OFF, out + XHAT_OFF);
}

// Round 3
// 776.327 us; speedup vs baseline: 2.5146x; 1.5487x over previous
//
#include <hip/hip_runtime.h>
#include <math.h>

#define B_    16384
#define IN_   64
#define DENC_ 512
#define NE_   2048
#define P_    12
#define ROWS_ 196608      // B_*P_
#define BETA_ 0.25

// output layout (all float32, concatenated in return order)
#define XHAT_OFF 1
#define PERP_OFF 1048577   // 1 + 16384*64
#define IDXF_OFF 1048578
#define COEF_OFF 1245186   // IDXF_OFF + 196608

typedef __bf16 bf16x8 __attribute__((ext_vector_type(8)));
typedef float  f32x16 __attribute__((ext_vector_type(16)));

__device__ __forceinline__ void split3(float v, __bf16& h, __bf16& m, __bf16& l) {
    h = (__bf16)v;
    float r1 = v - (float)h;
    m = (__bf16)r1;
    float r2 = r1 - (float)m;
    l = (__bf16)r2;
}

// ---------------------------------------------------------------------------
// Pre-split weights: W[K][N] f32 -> Wt planes [N][K] bf16 (hi/mid/lo).
// idx ordered [n][k] so plane writes are coalesced; K is pow2 (kshift).
// ---------------------------------------------------------------------------
__global__ void k_wsplit(const float* __restrict__ W,
                         __bf16* __restrict__ Wh, __bf16* __restrict__ Wm,
                         __bf16* __restrict__ Wl, int kshift, int N, int total) {
    int idx = blockIdx.x * 256 + threadIdx.x;
    if (idx < total) {
        int n = idx >> kshift;
        int k = idx & ((1 << kshift) - 1);
        float v = W[(size_t)k * N + n];
        __bf16 h, m, l;
        split3(v, h, m, l);
        Wh[idx] = h; Wm[idx] = m; Wl[idx] = l;
    }
}

// ---------------------------------------------------------------------------
// MFMA GEMM + bias: C[M][N] = A[M][K] @ W[K][N] + bias, via 3-term bf16 split
// of both operands (6 cross products). B given pre-split+transposed [N][K].
// Block = 128 rows x 64 cols, 4 waves x (32 rows x 64 cols).
// ---------------------------------------------------------------------------
__global__ __launch_bounds__(256) void k_gemm_mfma(const float* __restrict__ A,
                                                   const __bf16* __restrict__ Bh,
                                                   const __bf16* __restrict__ Bm,
                                                   const __bf16* __restrict__ Bl,
                                                   const float* __restrict__ bias,
                                                   float* __restrict__ C,
                                                   int N, int K) {
    __shared__ __bf16 eS[3][64 * 64];   // XOR-swizzled 16B granules

    const int tid = threadIdx.x;
    const int w = tid >> 6, lane = tid & 63;
    const int r0 = blockIdx.y * 128 + w * 32;
    const int n0 = blockIdx.x * 64;
    const int lrow = lane & 31;
    const int half = lane >> 5;

    f32x16 acc0, acc1;
#pragma unroll
    for (int i = 0; i < 16; ++i) { acc0[i] = 0.0f; acc1[i] = 0.0f; }

    for (int k0 = 0; k0 < K; k0 += 64) {
        __syncthreads();
        // stage B chunk: 64 cols x 64 k, 3 planes
        {
            const int col = tid >> 3, q = tid & 7;
#pragma unroll
            for (int p = 0; p < 2; ++p) {
                int cc = col + 32 * p;
                int g = q ^ (cc & 7);
                size_t soff = (size_t)(n0 + cc) * K + k0 + q * 8;
                int doff = cc * 64 + g * 8;
                *(float4*)(&eS[0][doff]) = *(const float4*)(Bh + soff);
                *(float4*)(&eS[1][doff]) = *(const float4*)(Bm + soff);
                *(float4*)(&eS[2][doff]) = *(const float4*)(Bl + soff);
            }
        }
        __syncthreads();

        // A fragments for this chunk: split f32 rows in-register
        bf16x8 ah[4], am[4], al[4];
        {
            const float* ar = A + (size_t)(r0 + lrow) * K + k0 + half * 8;
#pragma unroll
            for (int kc = 0; kc < 4; ++kc) {
                float4 u0 = *(const float4*)(ar + kc * 16);
                float4 u1 = *(const float4*)(ar + kc * 16 + 4);
                float v[8] = {u0.x, u0.y, u0.z, u0.w, u1.x, u1.y, u1.z, u1.w};
#pragma unroll
                for (int j = 0; j < 8; ++j) {
                    __bf16 hh, mm, ll;
                    split3(v[j], hh, mm, ll);
                    ah[kc][j] = hh; am[kc][j] = mm; al[kc][j] = ll;
                }
            }
        }

#pragma unroll
        for (int kc = 0; kc < 4; ++kc) {
            const int q = kc * 2 + half;
            const int g = (q ^ (lrow & 7)) * 8;
            bf16x8 b0h = *(const bf16x8*)(&eS[0][lrow * 64 + g]);
            bf16x8 b0m = *(const bf16x8*)(&eS[1][lrow * 64 + g]);
            bf16x8 b0l = *(const bf16x8*)(&eS[2][lrow * 64 + g]);
            bf16x8 b1h = *(const bf16x8*)(&eS[0][(lrow + 32) * 64 + g]);
            bf16x8 b1m = *(const bf16x8*)(&eS[1][(lrow + 32) * 64 + g]);
            bf16x8 b1l = *(const bf16x8*)(&eS[2][(lrow + 32) * 64 + g]);

            acc0 = __builtin_amdgcn_mfma_f32_32x32x16_bf16(ah[kc], b0h, acc0, 0, 0, 0);
            acc1 = __builtin_amdgcn_mfma_f32_32x32x16_bf16(ah[kc], b1h, acc1, 0, 0, 0);
            acc0 = __builtin_amdgcn_mfma_f32_32x32x16_bf16(ah[kc], b0m, acc0, 0, 0, 0);
            acc1 = __builtin_amdgcn_mfma_f32_32x32x16_bf16(ah[kc], b1m, acc1, 0, 0, 0);
            acc0 = __builtin_amdgcn_mfma_f32_32x32x16_bf16(am[kc], b0h, acc0, 0, 0, 0);
            acc1 = __builtin_amdgcn_mfma_f32_32x32x16_bf16(am[kc], b1h, acc1, 0, 0, 0);
            acc0 = __builtin_amdgcn_mfma_f32_32x32x16_bf16(ah[kc], b0l, acc0, 0, 0, 0);
            acc1 = __builtin_amdgcn_mfma_f32_32x32x16_bf16(ah[kc], b1l, acc1, 0, 0, 0);
            acc0 = __builtin_amdgcn_mfma_f32_32x32x16_bf16(am[kc], b0m, acc0, 0, 0, 0);
            acc1 = __builtin_amdgcn_mfma_f32_32x32x16_bf16(am[kc], b1m, acc1, 0, 0, 0);
            acc0 = __builtin_amdgcn_mfma_f32_32x32x16_bf16(al[kc], b0h, acc0, 0, 0, 0);
            acc1 = __builtin_amdgcn_mfma_f32_32x32x16_bf16(al[kc], b1h, acc1, 0, 0, 0);
        }
    }

    // epilogue: bias + store
    const int col0 = n0 + lrow, col1 = col0 + 32;
    const float bv0 = bias[col0], bv1 = bias[col1];
#pragma unroll
    for (int r = 0; r < 16; ++r) {
        int row = r0 + (r & 3) + 8 * (r >> 2) + 4 * half;
        C[(size_t)row * N + col0] = acc0[r] + bv0;
        C[(size_t)row * N + col1] = acc1[r] + bv1;
    }
}

// ---------------------------------------------------------------------------
// h = h + relu(layer_norm(t) * g + beta)
// ---------------------------------------------------------------------------
__global__ __launch_bounds__(256) void k_lnrelu(const float* __restrict__ t,
                                                float* __restrict__ h,
                                                const float* __restrict__ g,
                                                const float* __restrict__ beta) {
    const int tid = threadIdx.x;
    const int wv = tid >> 6, lane = tid & 63;
    const int row = blockIdx.x * 4 + wv;
    const float* tr = t + (size_t)row * DENC_;
    float* hr = h + (size_t)row * DENC_;

    float4 v0 = *(const float4*)(tr + lane * 4);
    float4 v1 = *(const float4*)(tr + 256 + lane * 4);

    float s = v0.x + v0.y + v0.z + v0.w + v1.x + v1.y + v1.z + v1.w;
#pragma unroll
    for (int m = 1; m < 64; m <<= 1) s += __shfl_xor(s, m);
    float mu = s / 512.0f;

    float d0x = v0.x - mu, d0y = v0.y - mu, d0z = v0.z - mu, d0w = v0.w - mu;
    float d1x = v1.x - mu, d1y = v1.y - mu, d1z = v1.z - mu, d1w = v1.w - mu;
    float vs = d0x * d0x + d0y * d0y + d0z * d0z + d0w * d0w +
               d1x * d1x + d1y * d1y + d1z * d1z + d1w * d1w;
#pragma unroll
    for (int m = 1; m < 64; m <<= 1) vs += __shfl_xor(vs, m);
    float var = vs / 512.0f;
    float rs = (float)(1.0 / sqrt((double)var + 1e-5));

    float4 g0 = *(const float4*)(g + lane * 4);
    float4 g1 = *(const float4*)(g + 256 + lane * 4);
    float4 b0 = *(const float4*)(beta + lane * 4);
    float4 b1 = *(const float4*)(beta + 256 + lane * 4);

    float4 h0 = *(float4*)(hr + lane * 4);
    float4 h1 = *(float4*)(hr + 256 + lane * 4);

    h0.x += fmaxf(d0x * rs * g0.x + b0.x, 0.0f);
    h0.y += fmaxf(d0y * rs * g0.y + b0.y, 0.0f);
    h0.z += fmaxf(d0z * rs * g0.z + b0.z, 0.0f);
    h0.w += fmaxf(d0w * rs * g0.w + b0.w, 0.0f);
    h1.x += fmaxf(d1x * rs * g1.x + b1.x, 0.0f);
    h1.y += fmaxf(d1y * rs * g1.y + b1.y, 0.0f);
    h1.z += fmaxf(d1z * rs * g1.z + b1.z, 0.0f);
    h1.w += fmaxf(d1w * rs * g1.w + b1.w, 0.0f);

    *(float4*)(hr + lane * 4) = h0;
    *(float4*)(hr + 256 + lane * 4) = h1;
}

// ---------------------------------------------------------------------------
// E -> se + 3-way bf16 split planes (hi/mid/lo)
// ---------------------------------------------------------------------------
__global__ void k_esplit(const float* __restrict__ emb, float* __restrict__ se,
                         __bf16* __restrict__ Ehi, __bf16* __restrict__ Emid,
                         __bf16* __restrict__ Elo) {
    int c = blockIdx.x * 256 + threadIdx.x;
    if (c < NE_) {
        float s = 0.0f;
        for (int k = 0; k < 64; ++k) {
            float v = emb[(size_t)c * 64 + k];
            s += v * v;
            __bf16 h, m, l;
            split3(v, h, m, l);
            Ehi[(size_t)c * 64 + k] = h;
            Emid[(size_t)c * 64 + k] = m;
            Elo[(size_t)c * 64 + k] = l;
        }
        se[c] = s;
    }
}

// ---------------------------------------------------------------------------
// sz[row] = sum(z[row]^2)
// ---------------------------------------------------------------------------
__global__ __launch_bounds__(256) void k_rowsq(const float* __restrict__ z,
                                               float* __restrict__ sz) {
    const int tid = threadIdx.x;
    const int row = blockIdx.x * 64 + (tid >> 2);
    const int part = tid & 3;
    const float4* zp = (const float4*)(z + (size_t)row * 64) + part * 4;
    float s = 0.0f;
#pragma unroll
    for (int i = 0; i < 4; ++i) {
        float4 v = zp[i];
        s += v.x * v.x + v.y * v.y + v.z * v.z + v.w * v.w;
    }
    s += __shfl_xor(s, 1);
    s += __shfl_xor(s, 2);
    if (part == 0) sz[row] = s;
}

// ---------------------------------------------------------------------------
// MFMA distance + argmin (verified in R1)
// ---------------------------------------------------------------------------
__global__ __launch_bounds__(256) void k_distm(const float* __restrict__ z,
                                               const float* __restrict__ se,
                                               const float* __restrict__ sz,
                                               const __bf16* __restrict__ Ehi,
                                               const __bf16* __restrict__ Emid,
                                               const __bf16* __restrict__ Elo,
                                               int* __restrict__ idxw,
                                               float* __restrict__ idxf,
                                               float* __restrict__ dminw,
                                               int* __restrict__ counts) {
    __shared__ __bf16 eS[3][64 * 64];

    const int tid = threadIdx.x;
    const int w = tid >> 6, lane = tid & 63;
    const int r0 = blockIdx.x * 128 + w * 32;
    const int lrow = lane & 31;
    const int half = lane >> 5;

    bf16x8 ah[4], am[4], al[4];
    {
        const float* zr = z + (size_t)(r0 + lrow) * 64 + half * 8;
#pragma unroll
        for (int kc = 0; kc < 4; ++kc) {
            float4 u0 = *(const float4*)(zr + kc * 16);
            float4 u1 = *(const float4*)(zr + kc * 16 + 4);
            float v[8] = {u0.x, u0.y, u0.z, u0.w, u1.x, u1.y, u1.z, u1.w};
#pragma unroll
            for (int j = 0; j < 8; ++j) {
                __bf16 hh, mm, ll;
                split3(v[j], hh, mm, ll);
                ah[kc][j] = hh; am[kc][j] = mm; al[kc][j] = ll;
            }
        }
    }

    float szv[16];
#pragma unroll
    for (int r = 0; r < 16; ++r) {
        int rl = (r & 3) + 8 * (r >> 2) + 4 * half;
        szv[r] = sz[r0 + rl];
    }

    float bd[16];
    int bi[16];
#pragma unroll
    for (int r = 0; r < 16; ++r) { bd[r] = 1e30f; bi[r] = 0; }

    for (int ch = 0; ch < 32; ++ch) {
        const int c0 = ch * 64;
        __syncthreads();
        {
            const int col = tid >> 3, q = tid & 7;
#pragma unroll
            for (int p = 0; p < 2; ++p) {
                int cc = col + 32 * p;
                int g = q ^ (cc & 7);
                size_t soff = (size_t)(c0 + cc) * 64 + q * 8;
                int doff = cc * 64 + g * 8;
                *(float4*)(&eS[0][doff]) = *(const float4*)(Ehi + soff);
                *(float4*)(&eS[1][doff]) = *(const float4*)(Emid + soff);
                *(float4*)(&eS[2][doff]) = *(const float4*)(Elo + soff);
            }
        }
        __syncthreads();

        f32x16 acc0, acc1;
#pragma unroll
        for (int i = 0; i < 16; ++i) { acc0[i] = 0.0f; acc1[i] = 0.0f; }

#pragma unroll
        for (int kc = 0; kc < 4; ++kc) {
            const int q = kc * 2 + half;
            const int g = (q ^ (lrow & 7)) * 8;
            bf16x8 b0h = *(const bf16x8*)(&eS[0][lrow * 64 + g]);
            bf16x8 b0m = *(const bf16x8*)(&eS[1][lrow * 64 + g]);
            bf16x8 b0l = *(const bf16x8*)(&eS[2][lrow * 64 + g]);
            bf16x8 b1h = *(const bf16x8*)(&eS[0][(lrow + 32) * 64 + g]);
            bf16x8 b1m = *(const bf16x8*)(&eS[1][(lrow + 32) * 64 + g]);
            bf16x8 b1l = *(const bf16x8*)(&eS[2][(lrow + 32) * 64 + g]);

            acc0 = __builtin_amdgcn_mfma_f32_32x32x16_bf16(ah[kc], b0h, acc0, 0, 0, 0);
            acc1 = __builtin_amdgcn_mfma_f32_32x32x16_bf16(ah[kc], b1h, acc1, 0, 0, 0);
            acc0 = __builtin_amdgcn_mfma_f32_32x32x16_bf16(ah[kc], b0m, acc0, 0, 0, 0);
            acc1 = __builtin_amdgcn_mfma_f32_32x32x16_bf16(ah[kc], b1m, acc1, 0, 0, 0);
            acc0 = __builtin_amdgcn_mfma_f32_32x32x16_bf16(am[kc], b0h, acc0, 0, 0, 0);
            acc1 = __builtin_amdgcn_mfma_f32_32x32x16_bf16(am[kc], b1h, acc1, 0, 0, 0);
            acc0 = __builtin_amdgcn_mfma_f32_32x32x16_bf16(ah[kc], b0l, acc0, 0, 0, 0);
            acc1 = __builtin_amdgcn_mfma_f32_32x32x16_bf16(ah[kc], b1l, acc1, 0, 0, 0);
            acc0 = __builtin_amdgcn_mfma_f32_32x32x16_bf16(am[kc], b0m, acc0, 0, 0, 0);
            acc1 = __builtin_amdgcn_mfma_f32_32x32x16_bf16(am[kc], b1m, acc1, 0, 0, 0);
            acc0 = __builtin_amdgcn_mfma_f32_32x32x16_bf16(al[kc], b0h, acc0, 0, 0, 0);
            acc1 = __builtin_amdgcn_mfma_f32_32x32x16_bf16(al[kc], b1h, acc1, 0, 0, 0);
        }

        const float se0 = se[c0 + lrow];
        const float se1 = se[c0 + lrow + 32];
        const int   ci0 = c0 + lrow, ci1 = c0 + lrow + 32;
#pragma unroll
        for (int r = 0; r < 16; ++r) {
            float d0 = fmaf(-2.0f, acc0[r], szv[r] + se0);
            if (d0 < bd[r]) { bd[r] = d0; bi[r] = ci0; }
            float d1 = fmaf(-2.0f, acc1[r], szv[r] + se1);
            if (d1 < bd[r]) { bd[r] = d1; bi[r] = ci1; }
        }
    }

#pragma unroll
    for (int r = 0; r < 16; ++r) {
        float d = bd[r];
        int i = bi[r];
#pragma unroll
        for (int off = 1; off < 32; off <<= 1) {
            float od = __shfl_xor(d, off);
            int oi = __shfl_xor(i, off);
            if (od < d || (od == d && oi < i)) { d = od; i = oi; }
        }
        bd[r] = d; bi[r] = i;
    }

    if (lrow == 0) {
#pragma unroll
        for (int r = 0; r < 16; ++r) {
            int rl = (r & 3) + 8 * (r >> 2) + 4 * half;
            int row = r0 + rl;
            idxw[row] = bi[r];
            idxf[row] = (float)bi[r];
            dminw[row] = bd[r];
            atomicAdd(&counts[bi[r]], 1);
        }
    }
}

// ---------------------------------------------------------------------------
// loss + perplexity
// ---------------------------------------------------------------------------
__global__ __launch_bounds__(1024) void k_lossperp(const float* __restrict__ dmin,
                                                   const int* __restrict__ counts,
                                                   float* __restrict__ out) {
    __shared__ double red[1024];
    const int tid = threadIdx.x;

    double s = 0.0;
    for (int i = tid; i < ROWS_; i += 1024) s += (double)dmin[i];
    red[tid] = s;
    __syncthreads();
    for (int off = 512; off > 0; off >>= 1) {
        if (tid < off) red[tid] += red[tid + off];
        __syncthreads();
    }
    if (tid == 0) out[0] = (float)(red[0] * (1.0 + BETA_) / ((double)ROWS_ * IN_));
    __syncthreads();

    double hsum = 0.0;
    for (int i = tid; i < NE_; i += 1024) {
        float p = (float)counts[i] / 196608.0f;
        float lg = logf(p + 1e-10f);
        hsum += (double)(p * lg);
    }
    red[tid] = hsum;
    __syncthreads();
    for (int off = 512; off > 0; off >>= 1) {
        if (tid < off) red[tid] += red[tid + off];
        __syncthreads();
    }
    if (tid == 0) out[PERP_OFF] = (float)exp(-red[0]);
}

// ---------------------------------------------------------------------------
// per-block pinv least-squares: coeff + x_hat (dedup -> min-norm, f64 Cholesky)
// ---------------------------------------------------------------------------
__global__ __launch_bounds__(256) void k_pinv(const float* __restrict__ xin,
                                              const float* __restrict__ emb,
                                              const int* __restrict__ idxw,
                                              float* __restrict__ coeff,
                                              float* __restrict__ xhat) {
    __shared__ float aS[4][12][65];
    __shared__ float xS[4][64];
    __shared__ double GS[4][12][12];
    __shared__ double bS[4][12];
    __shared__ double uS[4][12];
    __shared__ float cS[4][12];

    const int tid = threadIdx.x;
    const int wv = tid >> 6, lane = tid & 63;
    const int b = blockIdx.x * 4 + wv;

    int my = 0;
    if (lane < 12) my = idxw[(size_t)b * 12 + lane];
    int id[12];
#pragma unroll
    for (int p = 0; p < 12; ++p) id[p] = __shfl(my, p);

    int rep = lane, mcnt = 1;
    if (lane < 12) {
        rep = -1;
        mcnt = 0;
        for (int q = 0; q < 12; ++q) {
            if (id[q] == id[lane]) {
                if (rep < 0) rep = q;
                mcnt++;
            }
        }
    }

#pragma unroll
    for (int p = 0; p < 12; ++p) aS[wv][p][lane] = emb[(size_t)id[p] * 64 + lane];
    xS[wv][lane] = xin[(size_t)b * 64 + lane];
    __syncthreads();

    for (int item = lane; item < 90; item += 64) {
        if (item < 78) {
            int j = 0, k = 0, c = item;
            for (j = 0; j < 12; ++j) {
                int cnt = 12 - j;
                if (c < cnt) { k = j + c; break; }
                c -= cnt;
            }
            double s = 0.0;
            for (int t = 0; t < 64; ++t) s += (double)aS[wv][j][t] * (double)aS[wv][k][t];
            GS[wv][j][k] = s;
            GS[wv][k][j] = s;
        } else {
            int j = item - 78;
            double s = 0.0;
            for (int t = 0; t < 64; ++t) s += (double)aS[wv][j][t] * (double)xS[wv][t];
            bS[wv][j] = s;
        }
    }
    __syncthreads();

    if (lane == 0) {
        for (int p = 0; p < 12; ++p) {
            int rp = -1;
            for (int q = 0; q < 12; ++q) {
                if (id[q] == id[p]) { rp = q; break; }
            }
            if (rp != p) {
                for (int q = 0; q < 12; ++q) {
                    GS[wv][p][q] = 0.0;
                    GS[wv][q][p] = 0.0;
                }
                GS[wv][p][p] = 1.0;
                bS[wv][p] = 0.0;
            }
        }
    }
    __syncthreads();

    for (int j = 0; j < 12; ++j) {
        if (lane == j) {
            double s = GS[wv][j][j];
            for (int k = 0; k < j; ++k) {
                double l = GS[wv][j][k];
                s -= l * l;
            }
            GS[wv][j][j] = sqrt(fmax(s, 1e-30));
        }
        __syncthreads();
        if (lane > j && lane < 12) {
            double s = GS[wv][lane][j];
            for (int k = 0; k < j; ++k) s -= GS[wv][lane][k] * GS[wv][j][k];
            GS[wv][lane][j] = s / GS[wv][j][j];
        }
        __syncthreads();
    }

    if (lane == 0) {
        double y[12];
        for (int i = 0; i < 12; ++i) {
            double s = bS[wv][i];
            for (int k = 0; k < i; ++k) s -= GS[wv][i][k] * y[k];
            y[i] = s / GS[wv][i][i];
        }
        for (int i = 11; i >= 0; --i) {
            double s = y[i];
            for (int k = i + 1; k < 12; ++k) s -= GS[wv][k][i] * uS[wv][k];
            uS[wv][i] = s / GS[wv][i][i];
        }
    }
    __syncthreads();

    if (lane < 12) {
        double c = uS[wv][rep] / (double)mcnt;
        coeff[(size_t)b * 12 + lane] = (float)c;
        cS[wv][lane] = (float)c;
    }
    __syncthreads();

    float s = 0.0f;
#pragma unroll
    for (int p = 0; p < 12; ++p) s += aS[wv][p][lane] * cS[wv][p];
    xhat[(size_t)b * 64 + lane] = s;
}

// ---------------------------------------------------------------------------

extern "C" void kernel_launch(void* const* d_in, const int* in_sizes, int n_in,
                              void* d_out, int out_size, void* d_ws, size_t ws_size,
                              hipStream_t stream) {
    const float* x        = (const float*)d_in[0];
    const float* enc_w1   = (const float*)d_in[1];
    const float* enc_b1   = (const float*)d_in[2];
    const float* res_w    = (const float*)d_in[3];
    const float* res_b    = (const float*)d_in[4];
    const float* res_g    = (const float*)d_in[5];
    const float* res_beta = (const float*)d_in[6];
    const float* enc_w2   = (const float*)d_in[7];
    const float* enc_b2   = (const float*)d_in[8];
    const float* emb      = (const float*)d_in[9];

    float* out = (float*)d_out;

    // workspace layout
    float* h  = (float*)d_ws;            // B*512 f32 (32MB), reused after enc2
    float* tz = h + (size_t)B_ * DENC_;  // B*768 f32 (48MB): t then z
    // VQ scratch overlapping h (dead after enc2):
    float* se    = h;                                        // 2048
    float* sz    = h + 2048;                                 // ROWS_
    float* dmin  = h + 2048 + (size_t)ROWS_;                 // ROWS_
    int*   idxw  = (int*)(h + 2048 + 2 * (size_t)ROWS_);     // ROWS_
    int*   cnts  = (int*)(h + 2048 + 3 * (size_t)ROWS_);     // 2048
    __bf16* Ehi  = (__bf16*)(h + 2048 + 3 * (size_t)ROWS_ + 2048);
    __bf16* Emid = Ehi + (size_t)NE_ * 64;
    __bf16* Elo  = Emid + (size_t)NE_ * 64;
    // pre-split weight planes (transposed [N][K]) after tz:
    __bf16* W1h = (__bf16*)(tz + (size_t)B_ * 768);   // 512*64 each
    __bf16* W1m = W1h + (size_t)DENC_ * IN_;
    __bf16* W1l = W1m + (size_t)DENC_ * IN_;
    __bf16* Wrh = W1l + (size_t)DENC_ * IN_;          // 512*512 each
    __bf16* Wrm = Wrh + (size_t)DENC_ * DENC_;
    __bf16* Wrl = Wrm + (size_t)DENC_ * DENC_;
    __bf16* W2h = Wrl + (size_t)DENC_ * DENC_;        // 768*512 each
    __bf16* W2m = W2h + (size_t)768 * DENC_;
    __bf16* W2l = W2m + (size_t)768 * DENC_;

    float* t = tz;
    float* z = tz;

    // pre-split weights (transposed bf16 planes)
    k_wsplit<<<(DENC_ * IN_ + 255) / 256, 256, 0, stream>>>(enc_w1, W1h, W1m, W1l, 6, DENC_, DENC_ * IN_);
    k_wsplit<<<(DENC_ * DENC_ + 255) / 256, 256, 0, stream>>>(res_w, Wrh, Wrm, Wrl, 9, DENC_, DENC_ * DENC_);
    k_wsplit<<<(768 * DENC_ + 255) / 256, 256, 0, stream>>>(enc_w2, W2h, W2m, W2l, 9, 768, 768 * DENC_);

    // encoder (MFMA path)
    k_gemm_mfma<<<dim3(DENC_ / 64, B_ / 128), 256, 0, stream>>>(x, W1h, W1m, W1l, enc_b1, h, DENC_, IN_);
    for (int r = 0; r < 2; ++r) {
        k_gemm_mfma<<<dim3(DENC_ / 64, B_ / 128), 256, 0, stream>>>(h, Wrh, Wrm, Wrl, res_b, t, DENC_, DENC_);
        k_lnrelu<<<B_ / 4, 256, 0, stream>>>(t, h, res_g, res_beta);
    }
    k_gemm_mfma<<<dim3(768 / 64, B_ / 128), 256, 0, stream>>>(h, W2h, W2m, W2l, enc_b2, z, 768, DENC_);

    // VQ
    hipMemsetAsync(cnts, 0, NE_ * sizeof(int), stream);
    k_esplit<<<NE_ / 256, 256, 0, stream>>>(emb, se, Ehi, Emid, Elo);
    k_rowsq<<<ROWS_ / 64, 256, 0, stream>>>(z, sz);
    k_distm<<<ROWS_ / 128, 256, 0, stream>>>(z, se, sz, Ehi, Emid, Elo,
                                             idxw, out + IDXF_OFF, dmin, cnts);
    k_lossperp<<<1, 1024, 0, stream>>>(dmin, cnts, out);
    k_pinv<<<B_ / 4, 256, 0, stream>>>(x, emb, idxw, out + COEF_OFF, out + XHAT_OFF);
}